// Round 4
// baseline (351.725 us; speedup 1.0000x reference)
//
#include <hip/hip_runtime.h>

#define L_SEQ 2048
#define CS 384
#define CE 32
#define CIN 416
#define CH 128
#define NRES 20

#define ABST 136   // f16 LDS row stride (272 B = 17x16B, odd 16B-slots)

// ---- ws layout: [perm 8KB][f16 hi weights TOTW][f16 lo weights TOTW] ----
#define PERM_BYTES 8192
#define WA_PER (CH*CIN)
#define WB_PER (CH*CH)
#define WO_PER (16*CH)
#define OFF_WA1T 0
#define OFF_WA2T (NRES*WA_PER)
#define OFF_WB1AT (2*NRES*WA_PER)
#define OFF_WB1BT (OFF_WB1AT + 1*NRES*WB_PER)
#define OFF_WB2AT (OFF_WB1AT + 2*NRES*WB_PER)
#define OFF_WB2BT (OFF_WB1AT + 3*NRES*WB_PER)
#define OFF_WOUTT (OFF_WB1AT + 4*NRES*WB_PER)
#define TOTW (OFF_WOUTT + NRES*WO_PER)            // 3,481,600 elements
#define WS_NEED ((size_t)PERM_BYTES + (size_t)4*TOTW)  // 13,934,592 B

// output offsets (floats): quat_new, trsl_new, angl, quat_upd
#define OUT_TR 262144
#define OUT_ANG 458752
#define OUT_QU 1376256

#define LOSCALE 4096.0f
#define ILOSCALE (1.0f/4096.0f)
#define F16MIN 6.1035156e-5f

typedef _Float16 f16x8 __attribute__((ext_vector_type(8)));
typedef _Float16 f16x4 __attribute__((ext_vector_type(4)));
typedef float f32x4 __attribute__((ext_vector_type(4)));

#define MFMA16 __builtin_amdgcn_mfma_f32_16x16x32_f16

// ---------------- split helpers (x = hi + lo/4096, denormal-safe) ----------------
static __device__ __forceinline__ void split1(float x, _Float16& h, _Float16& l) {
  _Float16 hi = (__builtin_fabsf(x) < F16MIN) ? (_Float16)0.f : (_Float16)x;
  h = hi;
  l = (_Float16)((x - (float)hi) * LOSCALE);
}

static __device__ __forceinline__ void split8s(const float* x, f16x8& h, f16x8& l) {
  #pragma unroll
  for (int i = 0; i < 8; ++i) { _Float16 hh, ll; split1(x[i], hh, ll); h[i] = hh; l[i] = ll; }
}

static __device__ __forceinline__ void splitrelu4(const float4& v, f16x4& h, f16x4& l) {
  const float xs[4] = {v.x, v.y, v.z, v.w};
  #pragma unroll
  for (int i = 0; i < 4; ++i) {
    const float x = fmaxf(xs[i], 0.f);
    _Float16 hh, ll; split1(x, hh, ll); h[i] = hh; l[i] = ll;
  }
}

// ---------------- quat/trsl head: one wave per (n,l) — PASSING, unchanged ----------------
__global__ __launch_bounds__(256) void quat_head(
    const float* __restrict__ sfea, const float* __restrict__ encd,
    const float* __restrict__ quat, const float* __restrict__ trsl,
    const float* __restrict__ Wq, const float* __restrict__ bq,
    const float* __restrict__ Wt, const float* __restrict__ bt,
    float* __restrict__ out) {
  const int wv   = threadIdx.x >> 6;
  const int lane = threadIdx.x & 63;
  const size_t idx = (size_t)blockIdx.x * 4 + wv;
  const float* __restrict__ srow = sfea + idx * CS;

  float q0=0,q1=0,q2=0,q3=0,t0=0,t1=0,t2=0;
  #pragma unroll
  for (int cc = 0; cc < 6; ++cc) {
    const int ch = cc*64 + lane;
    const float s = srow[ch];
    const float* wq = Wq + (size_t)ch*4;
    const float* wt = Wt + (size_t)ch*3;
    q0 += s*wq[0]; q1 += s*wq[1]; q2 += s*wq[2]; q3 += s*wq[3];
    t0 += s*wt[0]; t1 += s*wt[1]; t2 += s*wt[2];
  }
  if (lane < CE) {
    const float s = encd[idx*CE + lane];
    const int ch = CS + lane;
    const float* wq = Wq + (size_t)ch*4;
    const float* wt = Wt + (size_t)ch*3;
    q0 += s*wq[0]; q1 += s*wq[1]; q2 += s*wq[2]; q3 += s*wq[3];
    t0 += s*wt[0]; t1 += s*wt[1]; t2 += s*wt[2];
  }
  #pragma unroll
  for (int off = 1; off < 64; off <<= 1) {
    q0 += __shfl_xor(q0, off); q1 += __shfl_xor(q1, off);
    q2 += __shfl_xor(q2, off); q3 += __shfl_xor(q3, off);
    t0 += __shfl_xor(t0, off); t1 += __shfl_xor(t1, off);
    t2 += __shfl_xor(t2, off);
  }
  if (lane == 0) {
    const float u0 = q0 + bq[0], u1 = q1 + bq[1], u2 = q2 + bq[2], u3 = q3 + bq[3];
    const float v0 = t0 + bt[0], v1 = t1 + bt[1], v2 = t2 + bt[2];
    float a0 = quat[idx*4+0], a1 = quat[idx*4+1], a2 = quat[idx*4+2], a3 = quat[idx*4+3];
    const float rq = rsqrtf(a0*a0+a1*a1+a2*a2+a3*a3 + 1e-8f);
    a0*=rq; a1*=rq; a2*=rq; a3*=rq;
    const float ru = rsqrtf(u0*u0+u1*u1+u2*u2+u3*u3 + 1e-8f);
    const float p0=u0*ru, p1=u1*ru, p2=u2*ru, p3=u3*ru;
    const float mw = a0*p0 - a1*p1 - a2*p2 - a3*p3;
    const float mx = a0*p1 + a1*p0 + a2*p3 - a3*p2;
    const float my = a0*p2 - a1*p3 + a2*p0 + a3*p1;
    const float mz = a0*p3 + a1*p2 - a2*p1 + a3*p0;
    const float rm = rsqrtf(mw*mw+mx*mx+my*my+mz*mz + 1e-8f);
    out[idx*4+0]=mw*rm; out[idx*4+1]=mx*rm; out[idx*4+2]=my*rm; out[idx*4+3]=mz*rm;
    const float tx = 2.f*(a2*v2 - a3*v1);
    const float ty = 2.f*(a3*v0 - a1*v2);
    const float tz = 2.f*(a1*v1 - a2*v0);
    out[OUT_TR + idx*3+0] = trsl[idx*3+0] + v0 + a0*tx + (a2*tz - a3*ty);
    out[OUT_TR + idx*3+1] = trsl[idx*3+1] + v1 + a0*ty + (a3*tx - a1*tz);
    out[OUT_TR + idx*3+2] = trsl[idx*3+2] + v2 + a0*tz + (a1*ty - a2*tx);
    out[OUT_QU + idx*4+0]=u0; out[OUT_QU + idx*4+1]=u1;
    out[OUT_QU + idx*4+2]=u2; out[OUT_QU + idx*4+3]=u3;
  }
}

// ---------------- aa-sorted l-permutation (deterministic, stable) ----------------
__global__ __launch_bounds__(256) void build_perm(const int* __restrict__ aa_seq,
                                                  int* __restrict__ perm) {
  __shared__ int aas[L_SEQ];
  __shared__ int cnt[NRES];
  __shared__ int base[NRES];
  const int t = threadIdx.x;
  for (int i = t; i < L_SEQ; i += 256) aas[i] = aa_seq[i];
  if (t < NRES) cnt[t] = 0;
  __syncthreads();
  for (int i = t; i < L_SEQ; i += 256) atomicAdd(&cnt[aas[i]], 1);
  __syncthreads();
  if (t == 0) { int s = 0; for (int a = 0; a < NRES; ++a) { base[a] = s; s += cnt[a]; } }
  __syncthreads();
  if (t < NRES) {
    int b = base[t];
    for (int l = 0; l < L_SEQ; ++l) if (aas[l] == t) perm[b++] = l;
  }
}

// ---------------- weight convert: f32 -> transposed f16 hi/lo pairs ----------------
__global__ __launch_bounds__(256) void convert_w(
    const float* __restrict__ Wa1, const float* __restrict__ Wa2,
    const float* __restrict__ Wb1a, const float* __restrict__ Wb1b,
    const float* __restrict__ Wb2a, const float* __restrict__ Wb2b,
    const float* __restrict__ Wout, _Float16* __restrict__ wsw) {
  const int idx = blockIdx.x * 256 + threadIdx.x;
  if (idx >= TOTW) return;
  float v;
  if (idx < OFF_WB1AT) {
    const int which = (idx < OFF_WA2T) ? 0 : 1;
    const float* W = which ? Wa2 : Wa1;
    int r = idx - which * OFF_WA2T;
    const int aa = r / WA_PER; r -= aa * WA_PER;
    const int h = r / CIN;     const int c = r - h * CIN;
    v = W[((size_t)aa*CIN + c)*CH + h];                 // -> ws[aa][h][c]
  } else if (idx < OFF_WOUTT) {
    int q = idx - OFF_WB1AT;
    const int which = q / (NRES*WB_PER);
    int r = q - which * (NRES*WB_PER);
    const float* W = (which==0)?Wb1a:(which==1)?Wb1b:(which==2)?Wb2a:Wb2b;
    const int aa = r / WB_PER; r -= aa * WB_PER;
    const int h = r / CH;      const int c = r - h * CH;
    v = W[((size_t)aa*CH + c)*CH + h];
  } else {
    int r = idx - OFF_WOUTT;
    const int aa = r / WO_PER; r -= aa * WO_PER;
    const int kk = r / CH;     const int c = r - kk * CH;
    v = (kk < 14) ? Wout[((size_t)aa*CH + c)*14 + kk] : 0.f;
  }
  _Float16 h, l; split1(v, h, l);
  wsw[idx] = h;
  wsw[(size_t)TOTW + idx] = l;
}

// ---------------- fragment helpers ----------------
static __device__ __forceinline__ void bfrag_f32(const float* __restrict__ W, int rs,
                                                 int kbase, int col, f16x8& h, f16x8& l) {
  float x[8];
  const float* p = W + (size_t)kbase * rs + col;
  #pragma unroll
  for (int j = 0; j < 8; ++j) x[j] = p[(size_t)j * rs];
  split8s(x, h, l);
}

static __device__ __forceinline__ void fold(f32x4 acc[2][2], const f32x4 accL[2][2],
                                            float b0, float b1) {
  #pragma unroll
  for (int m = 0; m < 2; ++m)
    #pragma unroll
    for (int i = 0; i < 4; ++i) {
      acc[m][0][i] += accL[m][0][i]*ILOSCALE + b0;
      acc[m][1][i] += accL[m][1][i]*ILOSCALE + b1;
    }
}

static __device__ __forceinline__ void store_relu_pair(_Float16* dh, _Float16* dl,
    const f32x4 acc[2][2], int lane, int h0) {
  const int lr = lane & 15;
  const int r0 = (lane >> 4) << 2;
  #pragma unroll
  for (int m = 0; m < 2; ++m)
    #pragma unroll
    for (int p = 0; p < 2; ++p)
      #pragma unroll
      for (int i = 0; i < 4; ++i) {
        const float v = fmaxf(acc[m][p][i], 0.f);
        _Float16 hh, ll; split1(v, hh, ll);
        const int idx = (m*16 + r0 + i)*ABST + h0 + p*16 + lr;
        dh[idx] = hh; dl[idx] = ll;
      }
}

// one matrix, one K-chunk of layer-A-style GEMM (A from LDS pair, K-stride CIN in ws)
template<bool USEWS>
static __device__ __forceinline__ void gemmA(
    const _Float16* aH, const _Float16* aL,
    const float* __restrict__ Wf, const _Float16* __restrict__ wH,
    int kbase, int nks, f32x4 acc[2][2], f32x4 accL[2][2], int lane, int h0) {
  const int lr = lane & 15;
  const int lk = (lane >> 4) << 3;
  #pragma unroll
  for (int ks = 0; ks < nks; ++ks) {
    const int kl = ks*32 + lk;         // LDS chunk-local k
    const int kg = kbase + kl;         // global k (weights)
    const f16x8 a0h = *(const f16x8*)(aH + lr*ABST + kl);
    const f16x8 a0l = *(const f16x8*)(aL + lr*ABST + kl);
    const f16x8 a1h = *(const f16x8*)(aH + (lr+16)*ABST + kl);
    const f16x8 a1l = *(const f16x8*)(aL + (lr+16)*ABST + kl);
    f16x8 b0h, b0l, b1h, b1l;
    if constexpr (USEWS) {
      const _Float16* p0 = wH + (size_t)(h0+lr)*CIN + kg;
      const _Float16* p1 = wH + (size_t)(h0+16+lr)*CIN + kg;
      b0h = *(const f16x8*)p0; b0l = *(const f16x8*)(p0 + TOTW);
      b1h = *(const f16x8*)p1; b1l = *(const f16x8*)(p1 + TOTW);
    } else {
      bfrag_f32(Wf, CH, kg, h0+lr,    b0h, b0l);
      bfrag_f32(Wf, CH, kg, h0+16+lr, b1h, b1l);
    }
    acc [0][0] = MFMA16(a0h, b0h, acc [0][0], 0,0,0);
    accL[0][0] = MFMA16(a0h, b0l, accL[0][0], 0,0,0);
    accL[0][0] = MFMA16(a0l, b0h, accL[0][0], 0,0,0);
    acc [1][0] = MFMA16(a1h, b0h, acc [1][0], 0,0,0);
    accL[1][0] = MFMA16(a1h, b0l, accL[1][0], 0,0,0);
    accL[1][0] = MFMA16(a1l, b0h, accL[1][0], 0,0,0);
    acc [0][1] = MFMA16(a0h, b1h, acc [0][1], 0,0,0);
    accL[0][1] = MFMA16(a0h, b1l, accL[0][1], 0,0,0);
    accL[0][1] = MFMA16(a0l, b1h, accL[0][1], 0,0,0);
    acc [1][1] = MFMA16(a1h, b1h, acc [1][1], 0,0,0);
    accL[1][1] = MFMA16(a1h, b1l, accL[1][1], 0,0,0);
    accL[1][1] = MFMA16(a1l, b1h, accL[1][1], 0,0,0);
  }
}

// mid-layer GEMM, K=128 (A from LDS pair, K-stride CH in ws)
template<bool USEWS>
static __device__ __forceinline__ void gemm128(
    const _Float16* aH, const _Float16* aL,
    const float* __restrict__ Wf, const _Float16* __restrict__ wH,
    f32x4 acc[2][2], f32x4 accL[2][2], int lane, int h0) {
  const int lr = lane & 15;
  const int lk = (lane >> 4) << 3;
  #pragma unroll
  for (int ks = 0; ks < 4; ++ks) {
    const int k = ks*32 + lk;
    const f16x8 a0h = *(const f16x8*)(aH + lr*ABST + k);
    const f16x8 a0l = *(const f16x8*)(aL + lr*ABST + k);
    const f16x8 a1h = *(const f16x8*)(aH + (lr+16)*ABST + k);
    const f16x8 a1l = *(const f16x8*)(aL + (lr+16)*ABST + k);
    f16x8 b0h, b0l, b1h, b1l;
    if constexpr (USEWS) {
      const _Float16* p0 = wH + (size_t)(h0+lr)*CH + k;
      const _Float16* p1 = wH + (size_t)(h0+16+lr)*CH + k;
      b0h = *(const f16x8*)p0; b0l = *(const f16x8*)(p0 + TOTW);
      b1h = *(const f16x8*)p1; b1l = *(const f16x8*)(p1 + TOTW);
    } else {
      bfrag_f32(Wf, CH, k, h0+lr,    b0h, b0l);
      bfrag_f32(Wf, CH, k, h0+16+lr, b1h, b1l);
    }
    acc [0][0] = MFMA16(a0h, b0h, acc [0][0], 0,0,0);
    accL[0][0] = MFMA16(a0h, b0l, accL[0][0], 0,0,0);
    accL[0][0] = MFMA16(a0l, b0h, accL[0][0], 0,0,0);
    acc [1][0] = MFMA16(a1h, b0h, acc [1][0], 0,0,0);
    accL[1][0] = MFMA16(a1h, b0l, accL[1][0], 0,0,0);
    accL[1][0] = MFMA16(a1l, b0h, accL[1][0], 0,0,0);
    acc [0][1] = MFMA16(a0h, b1h, acc [0][1], 0,0,0);
    accL[0][1] = MFMA16(a0h, b1l, accL[0][1], 0,0,0);
    accL[0][1] = MFMA16(a0l, b1h, accL[0][1], 0,0,0);
    acc [1][1] = MFMA16(a1h, b1h, acc [1][1], 0,0,0);
    accL[1][1] = MFMA16(a1h, b1l, accL[1][1], 0,0,0);
    accL[1][1] = MFMA16(a1l, b1h, accL[1][1], 0,0,0);
  }
}

// ---------------- angle net: one block per sequence position ----------------
template<bool USEWS>
__global__ __launch_bounds__(256, 2) void fah_main(
    const int* __restrict__ aa_seq, const int* __restrict__ perm,
    const float* __restrict__ sfea, const float* __restrict__ sfei,
    const float* __restrict__ encd,
    const float* __restrict__ Wa1, const float* __restrict__ Wa2,
    const float* __restrict__ Wb1a, const float* __restrict__ Wb1b,
    const float* __restrict__ Wb2a, const float* __restrict__ Wb2b,
    const float* __restrict__ Wout,
    const float* __restrict__ ba1, const float* __restrict__ ba2,
    const float* __restrict__ bb1a, const float* __restrict__ bb1b,
    const float* __restrict__ bb2a, const float* __restrict__ bb2b,
    const float* __restrict__ bout,
    const _Float16* __restrict__ wsw,
    float* __restrict__ out) {
  __shared__ _Float16 sHa[32*ABST], sLa[32*ABST], sHc[32*ABST], sLc[32*ABST];
  __shared__ _Float16 abH[32*ABST], abL[32*ABST], hbH[32*ABST], hbL[32*ABST];

  const int b  = blockIdx.x;
  const int sp = ((b & 7) << 8) | (b >> 3);       // XCD-grouped sorted position
  const int l  = perm ? perm[sp] : b;
  const int t  = threadIdx.x;
  const int aa = aa_seq[l];

  const int lane = t & 63;
  const int wv   = t >> 6;
  const int lr   = lane & 15;
  const int lk   = (lane >> 4) << 3;
  const int h0   = wv * 32;

  const f32x4 zz = {0.f, 0.f, 0.f, 0.f};
  f32x4 accA[2][2], accAL[2][2];
  #pragma unroll
  for (int m = 0; m < 2; ++m) { accA[m][0]=zz; accA[m][1]=zz; accAL[m][0]=zz; accAL[m][1]=zz; }

  const float* WfA1 = Wa1 + (size_t)aa*CIN*CH;
  const float* WfA2 = Wa2 + (size_t)aa*CIN*CH;
  const _Float16* wsA1 = wsw + OFF_WA1T + (size_t)aa*WA_PER;
  const _Float16* wsA2 = wsw + OFF_WA2T + (size_t)aa*WA_PER;

  // ---- layer A over 4 K-chunks (128,128,128,32) ----
  const int n  = t >> 3;
  const int sj = t & 7;
  #pragma unroll
  for (int ck = 0; ck < 4; ++ck) {
    const int koff = ck * 128;
    if (ck < 3) {
      const float* srow = sfea + ((size_t)n*L_SEQ + l)*CS + koff;
      const float* irow = sfei + ((size_t)n*L_SEQ + l)*CS + koff;
      #pragma unroll
      for (int u = 0; u < 4; ++u) {
        const int c = sj*16 + u*4;
        f16x4 h4, l4;
        splitrelu4(*reinterpret_cast<const float4*>(srow + c), h4, l4);
        *(f16x4*)(sHa + n*ABST + c) = h4;  *(f16x4*)(sLa + n*ABST + c) = l4;
        splitrelu4(*reinterpret_cast<const float4*>(irow + c), h4, l4);
        *(f16x4*)(sHc + n*ABST + c) = h4;  *(f16x4*)(sLc + n*ABST + c) = l4;
      }
    } else {
      const float* erow = encd + ((size_t)n*L_SEQ + l)*CE;
      const int c = sj*4;
      f16x4 h4, l4;
      splitrelu4(*reinterpret_cast<const float4*>(erow + c), h4, l4);
      *(f16x4*)(sHa + n*ABST + c) = h4;  *(f16x4*)(sLa + n*ABST + c) = l4;
      *(f16x4*)(sHc + n*ABST + c) = h4;  *(f16x4*)(sLc + n*ABST + c) = l4;
    }
    __syncthreads();
    const int nks = (ck < 3) ? 4 : 1;
    gemmA<USEWS>(sHa, sLa, WfA1, wsA1, koff, nks, accA, accAL, lane, h0);
    gemmA<USEWS>(sHc, sLc, WfA2, wsA2, koff, nks, accA, accAL, lane, h0);
    __syncthreads();
  }
  fold(accA, accAL,
       ba1[aa*CH + h0 + lr]      + ba2[aa*CH + h0 + lr],
       ba1[aa*CH + h0 + 16 + lr] + ba2[aa*CH + h0 + 16 + lr]);
  store_relu_pair(abH, abL, accA, lane, h0);
  __syncthreads();

  // ---- mid layers ----
  { // h = relu(a)@Wb1a + bb1a
    f32x4 acc[2][2], accL[2][2];
    #pragma unroll
    for (int m = 0; m < 2; ++m) { acc[m][0]=zz; acc[m][1]=zz; accL[m][0]=zz; accL[m][1]=zz; }
    gemm128<USEWS>(abH, abL, Wb1a + (size_t)aa*WB_PER,
                   wsw + OFF_WB1AT + (size_t)aa*WB_PER, acc, accL, lane, h0);
    fold(acc, accL, bb1a[aa*CH + h0 + lr], bb1a[aa*CH + h0 + 16 + lr]);
    store_relu_pair(hbH, hbL, acc, lane, h0);
  }
  __syncthreads();
  { // a += relu(h)@Wb1b + bb1b
    f32x4 accL[2][2];
    #pragma unroll
    for (int m = 0; m < 2; ++m) { accL[m][0]=zz; accL[m][1]=zz; }
    gemm128<USEWS>(hbH, hbL, Wb1b + (size_t)aa*WB_PER,
                   wsw + OFF_WB1BT + (size_t)aa*WB_PER, accA, accL, lane, h0);
    fold(accA, accL, bb1b[aa*CH + h0 + lr], bb1b[aa*CH + h0 + 16 + lr]);
    store_relu_pair(abH, abL, accA, lane, h0);
  }
  __syncthreads();
  { // h = relu(a)@Wb2a + bb2a
    f32x4 acc[2][2], accL[2][2];
    #pragma unroll
    for (int m = 0; m < 2; ++m) { acc[m][0]=zz; acc[m][1]=zz; accL[m][0]=zz; accL[m][1]=zz; }
    gemm128<USEWS>(abH, abL, Wb2a + (size_t)aa*WB_PER,
                   wsw + OFF_WB2AT + (size_t)aa*WB_PER, acc, accL, lane, h0);
    fold(acc, accL, bb2a[aa*CH + h0 + lr], bb2a[aa*CH + h0 + 16 + lr]);
    store_relu_pair(hbH, hbL, acc, lane, h0);
  }
  __syncthreads();
  { // a += relu(h)@Wb2b + bb2b
    f32x4 accL[2][2];
    #pragma unroll
    for (int m = 0; m < 2; ++m) { accL[m][0]=zz; accL[m][1]=zz; }
    gemm128<USEWS>(hbH, hbL, Wb2b + (size_t)aa*WB_PER,
                   wsw + OFF_WB2BT + (size_t)aa*WB_PER, accA, accL, lane, h0);
    fold(accA, accL, bb2b[aa*CH + h0 + lr], bb2b[aa*CH + h0 + 16 + lr]);
    store_relu_pair(abH, abL, accA, lane, h0);
  }
  __syncthreads();

  // ---- out layer: relu(a) @ Wout (cols padded 14->16), pair-normalize ----
  if (wv < 2) {
    f32x4 o = zz, oL = zz;
    #pragma unroll
    for (int ks = 0; ks < 4; ++ks) {
      const int k = ks*32 + lk;
      const f16x8 ah = *(const f16x8*)(abH + (wv*16 + lr)*ABST + k);
      const f16x8 al = *(const f16x8*)(abL + (wv*16 + lr)*ABST + k);
      f16x8 bh, bl;
      if constexpr (USEWS) {
        const _Float16* p = wsw + OFF_WOUTT + (size_t)aa*WO_PER + (size_t)lr*CH + k;
        bh = *(const f16x8*)p; bl = *(const f16x8*)(p + TOTW);
      } else {
        if (lr < 14) {
          bfrag_f32(Wout + (size_t)aa*CH*14, 14, k, lr, bh, bl);
        } else {
          #pragma unroll
          for (int j = 0; j < 8; ++j) { bh[j] = (_Float16)0.f; bl[j] = (_Float16)0.f; }
        }
      }
      o  = MFMA16(ah, bh, o,  0,0,0);
      oL = MFMA16(ah, bl, oL, 0,0,0);
      oL = MFMA16(al, bh, oL, 0,0,0);
    }
    const float bo = (lr < 14) ? bout[aa*14 + lr] : 0.f;
    #pragma unroll
    for (int i = 0; i < 4; ++i) {
      const float v  = o[i] + oL[i]*ILOSCALE + bo;
      const float pv = __shfl_xor(v, 1);
      const float r  = rsqrtf(v*v + pv*pv + 1e-12f);
      if (lr < 14) {
        const int nrow = wv*16 + ((lane >> 4) << 2) + i;
        out[OUT_ANG + (size_t)nrow*(L_SEQ*14) + (size_t)l*14 + lr] = v*r;
      }
    }
  }
}

extern "C" void kernel_launch(void* const* d_in, const int* in_sizes, int n_in,
                              void* d_out, int out_size, void* d_ws, size_t ws_size,
                              hipStream_t stream) {
  const int*   aa   = (const int*)  d_in[0];
  const float* sfea = (const float*)d_in[1];
  const float* sfei = (const float*)d_in[2];
  const float* encd = (const float*)d_in[3];
  const float* quat = (const float*)d_in[4];
  const float* trsl = (const float*)d_in[5];
  const float* Wq   = (const float*)d_in[6];
  const float* bq   = (const float*)d_in[7];
  const float* Wt   = (const float*)d_in[8];
  const float* bt   = (const float*)d_in[9];
  const float* Wa1  = (const float*)d_in[10];
  const float* ba1  = (const float*)d_in[11];
  const float* Wa2  = (const float*)d_in[12];
  const float* ba2  = (const float*)d_in[13];
  const float* Wb1a = (const float*)d_in[14];
  const float* bb1a = (const float*)d_in[15];
  const float* Wb1b = (const float*)d_in[16];
  const float* bb1b = (const float*)d_in[17];
  const float* Wb2a = (const float*)d_in[18];
  const float* bb2a = (const float*)d_in[19];
  const float* Wb2b = (const float*)d_in[20];
  const float* bb2b = (const float*)d_in[21];
  const float* Wout = (const float*)d_in[22];
  const float* bout = (const float*)d_in[23];
  float* out = (float*)d_out;

  const bool useperm = ws_size >= (size_t)PERM_BYTES;
  const bool usews   = ws_size >= WS_NEED;
  int* perm = useperm ? (int*)d_ws : nullptr;
  _Float16* wsw = (_Float16*)((char*)d_ws + PERM_BYTES);

  if (useperm)
    hipLaunchKernelGGL(build_perm, dim3(1), dim3(256), 0, stream, aa, perm);
  if (usews)
    hipLaunchKernelGGL(convert_w, dim3((TOTW + 255)/256), dim3(256), 0, stream,
                       Wa1, Wa2, Wb1a, Wb1b, Wb2a, Wb2b, Wout, wsw);
  hipLaunchKernelGGL(quat_head, dim3(16384), dim3(256), 0, stream,
                     sfea, encd, quat, trsl, Wq, bq, Wt, bt, out);
  if (usews)
    hipLaunchKernelGGL((fah_main<true>), dim3(L_SEQ), dim3(256), 0, stream,
                       aa, perm, sfea, sfei, encd,
                       Wa1, Wa2, Wb1a, Wb1b, Wb2a, Wb2b, Wout,
                       ba1, ba2, bb1a, bb1b, bb2a, bb2b, bout, wsw, out);
  else
    hipLaunchKernelGGL((fah_main<false>), dim3(L_SEQ), dim3(256), 0, stream,
                       aa, perm, sfea, sfei, encd,
                       Wa1, Wa2, Wb1a, Wb1b, Wb2a, Wb2b, Wout,
                       ba1, ba2, bb1a, bb1b, bb2a, bb2b, bout, wsw, out);
}

// Round 5
// 219.291 us; speedup vs baseline: 1.6039x; 1.6039x over previous
//
#include <hip/hip_runtime.h>

#define L_SEQ 2048
#define CS 384
#define CE 32
#define CIN 416
#define CH 128
#define NRES 20

#define ABST 136   // f16 LDS row stride (272 B = 17x16B slots)

// ---- ws layout: [perm 8KB][f16 hi weights TOTW][f16 lo weights TOTW] ----
#define PERM_BYTES 8192
#define WA_PER (CH*CIN)
#define WB_PER (CH*CH)
#define WO_PER (16*CH)
#define OFF_WA1T 0
#define OFF_WA2T (NRES*WA_PER)
#define OFF_WB1AT (2*NRES*WA_PER)
#define OFF_WB1BT (OFF_WB1AT + 1*NRES*WB_PER)
#define OFF_WB2AT (OFF_WB1AT + 2*NRES*WB_PER)
#define OFF_WB2BT (OFF_WB1AT + 3*NRES*WB_PER)
#define OFF_WOUTT (OFF_WB1AT + 4*NRES*WB_PER)
#define TOTW (OFF_WOUTT + NRES*WO_PER)            // 3,481,600 elements
#define WS_NEED ((size_t)PERM_BYTES + (size_t)4*TOTW)  // 13,934,592 B

// output offsets (floats): quat_new, trsl_new, angl, quat_upd
#define OUT_TR 262144
#define OUT_ANG 458752
#define OUT_QU 1376256

#define LOSCALE 4096.0f
#define ILOSCALE (1.0f/4096.0f)
#define F16MIN 6.1035156e-5f

typedef _Float16 f16x8 __attribute__((ext_vector_type(8)));
typedef _Float16 f16x4 __attribute__((ext_vector_type(4)));
typedef float f32x4 __attribute__((ext_vector_type(4)));

#define MFMA16 __builtin_amdgcn_mfma_f32_16x16x32_f16

// ---------------- split helpers (x = hi + lo/4096, denormal-safe) ----------------
static __device__ __forceinline__ void split1(float x, _Float16& h, _Float16& l) {
  _Float16 hi = (__builtin_fabsf(x) < F16MIN) ? (_Float16)0.f : (_Float16)x;
  h = hi;
  l = (_Float16)((x - (float)hi) * LOSCALE);
}

static __device__ __forceinline__ void split8s(const float* x, f16x8& h, f16x8& l) {
  #pragma unroll
  for (int i = 0; i < 8; ++i) { _Float16 hh, ll; split1(x[i], hh, ll); h[i] = hh; l[i] = ll; }
}

static __device__ __forceinline__ void splitrelu4(const float4& v, f16x4& h, f16x4& l) {
  const float xs[4] = {v.x, v.y, v.z, v.w};
  #pragma unroll
  for (int i = 0; i < 4; ++i) {
    const float x = fmaxf(xs[i], 0.f);
    _Float16 hh, ll; split1(x, hh, ll); h[i] = hh; l[i] = ll;
  }
}

// ---------------- quat/trsl head: one wave per (n,l) — PASSING, unchanged ----------------
__global__ __launch_bounds__(256) void quat_head(
    const float* __restrict__ sfea, const float* __restrict__ encd,
    const float* __restrict__ quat, const float* __restrict__ trsl,
    const float* __restrict__ Wq, const float* __restrict__ bq,
    const float* __restrict__ Wt, const float* __restrict__ bt,
    float* __restrict__ out) {
  const int wv   = threadIdx.x >> 6;
  const int lane = threadIdx.x & 63;
  const size_t idx = (size_t)blockIdx.x * 4 + wv;
  const float* __restrict__ srow = sfea + idx * CS;

  float q0=0,q1=0,q2=0,q3=0,t0=0,t1=0,t2=0;
  #pragma unroll
  for (int cc = 0; cc < 6; ++cc) {
    const int ch = cc*64 + lane;
    const float s = srow[ch];
    const float4 wq = *reinterpret_cast<const float4*>(Wq + (size_t)ch*4);
    const float* wt = Wt + (size_t)ch*3;
    q0 += s*wq.x; q1 += s*wq.y; q2 += s*wq.z; q3 += s*wq.w;
    t0 += s*wt[0]; t1 += s*wt[1]; t2 += s*wt[2];
  }
  if (lane < CE) {
    const float s = encd[idx*CE + lane];
    const int ch = CS + lane;
    const float4 wq = *reinterpret_cast<const float4*>(Wq + (size_t)ch*4);
    const float* wt = Wt + (size_t)ch*3;
    q0 += s*wq.x; q1 += s*wq.y; q2 += s*wq.z; q3 += s*wq.w;
    t0 += s*wt[0]; t1 += s*wt[1]; t2 += s*wt[2];
  }
  #pragma unroll
  for (int off = 1; off < 64; off <<= 1) {
    q0 += __shfl_xor(q0, off); q1 += __shfl_xor(q1, off);
    q2 += __shfl_xor(q2, off); q3 += __shfl_xor(q3, off);
    t0 += __shfl_xor(t0, off); t1 += __shfl_xor(t1, off);
    t2 += __shfl_xor(t2, off);
  }
  if (lane == 0) {
    const float u0 = q0 + bq[0], u1 = q1 + bq[1], u2 = q2 + bq[2], u3 = q3 + bq[3];
    const float v0 = t0 + bt[0], v1 = t1 + bt[1], v2 = t2 + bt[2];
    float a0 = quat[idx*4+0], a1 = quat[idx*4+1], a2 = quat[idx*4+2], a3 = quat[idx*4+3];
    const float rq = rsqrtf(a0*a0+a1*a1+a2*a2+a3*a3 + 1e-8f);
    a0*=rq; a1*=rq; a2*=rq; a3*=rq;
    const float ru = rsqrtf(u0*u0+u1*u1+u2*u2+u3*u3 + 1e-8f);
    const float p0=u0*ru, p1=u1*ru, p2=u2*ru, p3=u3*ru;
    const float mw = a0*p0 - a1*p1 - a2*p2 - a3*p3;
    const float mx = a0*p1 + a1*p0 + a2*p3 - a3*p2;
    const float my = a0*p2 - a1*p3 + a2*p0 + a3*p1;
    const float mz = a0*p3 + a1*p2 - a2*p1 + a3*p0;
    const float rm = rsqrtf(mw*mw+mx*mx+my*my+mz*mz + 1e-8f);
    out[idx*4+0]=mw*rm; out[idx*4+1]=mx*rm; out[idx*4+2]=my*rm; out[idx*4+3]=mz*rm;
    const float tx = 2.f*(a2*v2 - a3*v1);
    const float ty = 2.f*(a3*v0 - a1*v2);
    const float tz = 2.f*(a1*v1 - a2*v0);
    out[OUT_TR + idx*3+0] = trsl[idx*3+0] + v0 + a0*tx + (a2*tz - a3*ty);
    out[OUT_TR + idx*3+1] = trsl[idx*3+1] + v1 + a0*ty + (a3*tx - a1*tz);
    out[OUT_TR + idx*3+2] = trsl[idx*3+2] + v2 + a0*tz + (a1*ty - a2*tx);
    out[OUT_QU + idx*4+0]=u0; out[OUT_QU + idx*4+1]=u1;
    out[OUT_QU + idx*4+2]=u2; out[OUT_QU + idx*4+3]=u3;
  }
}

// ------- aa-grouped l-permutation: ballot counting sort, fully wave-parallel -------
__global__ __launch_bounds__(1024) void build_perm(const int* __restrict__ aa_seq,
                                                   int* __restrict__ perm) {
  __shared__ int cnt[NRES*32];   // [a][window]
  __shared__ int off[NRES*32];
  const int t = threadIdx.x;
  const int wv = t >> 6, lane = t & 63;

  int aav[2];
  #pragma unroll
  for (int h = 0; h < 2; ++h) {
    const int W = wv + h*16;                 // window 0..31, 64 positions each
    aav[h] = aa_seq[W*64 + lane];
    #pragma unroll
    for (int a = 0; a < NRES; ++a) {
      const unsigned long long m = __ballot(aav[h] == a);
      if (lane == a) cnt[a*32 + W] = (int)__popcll(m);
    }
  }
  __syncthreads();
  if (t < 64) {   // exclusive prefix over flattened [a][W] (640 entries), wave-scan
    int carry = 0;
    #pragma unroll
    for (int c = 0; c < 10; ++c) {
      const int v0 = cnt[c*64 + t];
      int v = v0;
      #pragma unroll
      for (int o = 1; o < 64; o <<= 1) {
        const int u = __shfl_up(v, o);
        if (lane >= o) v += u;
      }
      off[c*64 + t] = carry + v - v0;
      carry += __shfl(v, 63);
    }
  }
  __syncthreads();
  const unsigned long long ltmask = (lane == 0) ? 0ull : (~0ull >> (64 - lane));
  #pragma unroll
  for (int h = 0; h < 2; ++h) {
    const int W = wv + h*16;
    const int aa = aav[h];
    int pos = 0;
    #pragma unroll
    for (int a = 0; a < NRES; ++a) {
      const unsigned long long m = __ballot(aa == a);
      if (aa == a) pos = off[a*32 + W] + (int)__popcll(m & ltmask);
    }
    perm[pos] = W*64 + lane;
  }
}

// ---------------- weight convert: f32 -> transposed f16 hi/lo pairs ----------------
__global__ __launch_bounds__(256) void convert_w(
    const float* __restrict__ Wa1, const float* __restrict__ Wa2,
    const float* __restrict__ Wb1a, const float* __restrict__ Wb1b,
    const float* __restrict__ Wb2a, const float* __restrict__ Wb2b,
    const float* __restrict__ Wout, _Float16* __restrict__ wsw) {
  const int idx = blockIdx.x * 256 + threadIdx.x;
  if (idx >= TOTW) return;
  float v;
  if (idx < OFF_WB1AT) {
    const int which = (idx < OFF_WA2T) ? 0 : 1;
    const float* W = which ? Wa2 : Wa1;
    int r = idx - which * OFF_WA2T;
    const int aa = r / WA_PER; r -= aa * WA_PER;
    const int h = r / CIN;     const int c = r - h * CIN;
    v = W[((size_t)aa*CIN + c)*CH + h];                 // -> ws[aa][h][c]
  } else if (idx < OFF_WOUTT) {
    int q = idx - OFF_WB1AT;
    const int which = q / (NRES*WB_PER);
    int r = q - which * (NRES*WB_PER);
    const float* W = (which==0)?Wb1a:(which==1)?Wb1b:(which==2)?Wb2a:Wb2b;
    const int aa = r / WB_PER; r -= aa * WB_PER;
    const int h = r / CH;      const int c = r - h * CH;
    v = W[((size_t)aa*CH + c)*CH + h];
  } else {
    int r = idx - OFF_WOUTT;
    const int aa = r / WO_PER; r -= aa * WO_PER;
    const int kk = r / CH;     const int c = r - kk * CH;
    v = (kk < 14) ? Wout[((size_t)aa*CH + c)*14 + kk] : 0.f;
  }
  _Float16 h, l; split1(v, h, l);
  wsw[idx] = h;
  wsw[(size_t)TOTW + idx] = l;
}

// ---------------- fragment helpers ----------------
static __device__ __forceinline__ void bfrag_f32(const float* __restrict__ W, int rs,
                                                 int kbase, int col, f16x8& h, f16x8& l) {
  float x[8];
  const float* p = W + (size_t)kbase * rs + col;
  #pragma unroll
  for (int j = 0; j < 8; ++j) x[j] = p[(size_t)j * rs];
  split8s(x, h, l);
}

static __device__ __forceinline__ void fold(f32x4 acc[2][2], const f32x4 accL[2][2],
                                            float b0, float b1) {
  #pragma unroll
  for (int m = 0; m < 2; ++m)
    #pragma unroll
    for (int i = 0; i < 4; ++i) {
      acc[m][0][i] += accL[m][0][i]*ILOSCALE + b0;
      acc[m][1][i] += accL[m][1][i]*ILOSCALE + b1;
    }
}

static __device__ __forceinline__ void store_relu_pair(_Float16* dh, _Float16* dl,
    const f32x4 acc[2][2], int lane, int h0) {
  const int lr = lane & 15;
  const int r0 = (lane >> 4) << 2;
  #pragma unroll
  for (int m = 0; m < 2; ++m)
    #pragma unroll
    for (int p = 0; p < 2; ++p)
      #pragma unroll
      for (int i = 0; i < 4; ++i) {
        const float v = fmaxf(acc[m][p][i], 0.f);
        _Float16 hh, ll; split1(v, hh, ll);
        const int idx = (m*16 + r0 + i)*ABST + h0 + p*16 + lr;
        dh[idx] = hh; dl[idx] = ll;
      }
}

// one matrix, one K-chunk of layer-A-style GEMM (A from LDS pair, K-stride CIN in ws)
template<bool USEWS>
static __device__ __forceinline__ void gemmA(
    const _Float16* aH, const _Float16* aL,
    const float* __restrict__ Wf, const _Float16* __restrict__ wH,
    int kbase, int nks, f32x4 acc[2][2], f32x4 accL[2][2], int lane, int h0) {
  const int lr = lane & 15;
  const int lk = (lane >> 4) << 3;
  #pragma unroll
  for (int ks = 0; ks < nks; ++ks) {
    const int kl = ks*32 + lk;         // LDS chunk-local k
    const int kg = kbase + kl;         // global k (weights)
    const f16x8 a0h = *(const f16x8*)(aH + lr*ABST + kl);
    const f16x8 a0l = *(const f16x8*)(aL + lr*ABST + kl);
    const f16x8 a1h = *(const f16x8*)(aH + (lr+16)*ABST + kl);
    const f16x8 a1l = *(const f16x8*)(aL + (lr+16)*ABST + kl);
    f16x8 b0h, b0l, b1h, b1l;
    if constexpr (USEWS) {
      const _Float16* p0 = wH + (size_t)(h0+lr)*CIN + kg;
      const _Float16* p1 = wH + (size_t)(h0+16+lr)*CIN + kg;
      b0h = *(const f16x8*)p0; b0l = *(const f16x8*)(p0 + TOTW);
      b1h = *(const f16x8*)p1; b1l = *(const f16x8*)(p1 + TOTW);
    } else {
      bfrag_f32(Wf, CH, kg, h0+lr,    b0h, b0l);
      bfrag_f32(Wf, CH, kg, h0+16+lr, b1h, b1l);
    }
    acc [0][0] = MFMA16(a0h, b0h, acc [0][0], 0,0,0);
    accL[0][0] = MFMA16(a0h, b0l, accL[0][0], 0,0,0);
    accL[0][0] = MFMA16(a0l, b0h, accL[0][0], 0,0,0);
    acc [1][0] = MFMA16(a1h, b0h, acc [1][0], 0,0,0);
    accL[1][0] = MFMA16(a1h, b0l, accL[1][0], 0,0,0);
    accL[1][0] = MFMA16(a1l, b0h, accL[1][0], 0,0,0);
    acc [0][1] = MFMA16(a0h, b1h, acc [0][1], 0,0,0);
    accL[0][1] = MFMA16(a0h, b1l, accL[0][1], 0,0,0);
    accL[0][1] = MFMA16(a0l, b1h, accL[0][1], 0,0,0);
    acc [1][1] = MFMA16(a1h, b1h, acc [1][1], 0,0,0);
    accL[1][1] = MFMA16(a1h, b1l, accL[1][1], 0,0,0);
    accL[1][1] = MFMA16(a1l, b1h, accL[1][1], 0,0,0);
  }
}

// mid-layer GEMM, K=128 (A from LDS pair, K-stride CH in ws)
template<bool USEWS>
static __device__ __forceinline__ void gemm128(
    const _Float16* aH, const _Float16* aL,
    const float* __restrict__ Wf, const _Float16* __restrict__ wH,
    f32x4 acc[2][2], f32x4 accL[2][2], int lane, int h0) {
  const int lr = lane & 15;
  const int lk = (lane >> 4) << 3;
  #pragma unroll
  for (int ks = 0; ks < 4; ++ks) {
    const int k = ks*32 + lk;
    const f16x8 a0h = *(const f16x8*)(aH + lr*ABST + k);
    const f16x8 a0l = *(const f16x8*)(aL + lr*ABST + k);
    const f16x8 a1h = *(const f16x8*)(aH + (lr+16)*ABST + k);
    const f16x8 a1l = *(const f16x8*)(aL + (lr+16)*ABST + k);
    f16x8 b0h, b0l, b1h, b1l;
    if constexpr (USEWS) {
      const _Float16* p0 = wH + (size_t)(h0+lr)*CH + k;
      const _Float16* p1 = wH + (size_t)(h0+16+lr)*CH + k;
      b0h = *(const f16x8*)p0; b0l = *(const f16x8*)(p0 + TOTW);
      b1h = *(const f16x8*)p1; b1l = *(const f16x8*)(p1 + TOTW);
    } else {
      bfrag_f32(Wf, CH, k, h0+lr,    b0h, b0l);
      bfrag_f32(Wf, CH, k, h0+16+lr, b1h, b1l);
    }
    acc [0][0] = MFMA16(a0h, b0h, acc [0][0], 0,0,0);
    accL[0][0] = MFMA16(a0h, b0l, accL[0][0], 0,0,0);
    accL[0][0] = MFMA16(a0l, b0h, accL[0][0], 0,0,0);
    acc [1][0] = MFMA16(a1h, b0h, acc [1][0], 0,0,0);
    accL[1][0] = MFMA16(a1h, b0l, accL[1][0], 0,0,0);
    accL[1][0] = MFMA16(a1l, b0h, accL[1][0], 0,0,0);
    acc [0][1] = MFMA16(a0h, b1h, acc [0][1], 0,0,0);
    accL[0][1] = MFMA16(a0h, b1l, accL[0][1], 0,0,0);
    accL[0][1] = MFMA16(a0l, b1h, accL[0][1], 0,0,0);
    acc [1][1] = MFMA16(a1h, b1h, acc [1][1], 0,0,0);
    accL[1][1] = MFMA16(a1h, b1l, accL[1][1], 0,0,0);
    accL[1][1] = MFMA16(a1l, b1h, accL[1][1], 0,0,0);
  }
}

// ---------------- angle net: one block per sequence position ----------------
// LDS: 4 arrays only (34.8 KB) -> 4 blocks/CU. Layer A stages sfea into s1,
// sfei into s2; after layer A, s1 becomes the "ab" buffer and s2 the "hb"
// buffer (ping-pong). All reuse is separated by __syncthreads.
template<bool USEWS>
__global__ __launch_bounds__(256, 4) void fah_main(
    const int* __restrict__ aa_seq, const int* __restrict__ perm,
    const float* __restrict__ sfea, const float* __restrict__ sfei,
    const float* __restrict__ encd,
    const float* __restrict__ Wa1, const float* __restrict__ Wa2,
    const float* __restrict__ Wb1a, const float* __restrict__ Wb1b,
    const float* __restrict__ Wb2a, const float* __restrict__ Wb2b,
    const float* __restrict__ Wout,
    const float* __restrict__ ba1, const float* __restrict__ ba2,
    const float* __restrict__ bb1a, const float* __restrict__ bb1b,
    const float* __restrict__ bb2a, const float* __restrict__ bb2b,
    const float* __restrict__ bout,
    const _Float16* __restrict__ wsw,
    float* __restrict__ out) {
  __shared__ _Float16 s1H[32*ABST], s1L[32*ABST], s2H[32*ABST], s2L[32*ABST];
  _Float16* abH = s1H;  _Float16* abL = s1L;
  _Float16* hbH = s2H;  _Float16* hbL = s2L;

  const int b  = blockIdx.x;
  const int sp = ((b & 7) << 8) | (b >> 3);       // XCD-grouped sorted position
  const int l  = perm ? perm[sp] : b;
  const int t  = threadIdx.x;
  const int aa = aa_seq[l];

  const int lane = t & 63;
  const int wv   = t >> 6;
  const int lr   = lane & 15;
  const int lk   = (lane >> 4) << 3;
  const int h0   = wv * 32;

  const f32x4 zz = {0.f, 0.f, 0.f, 0.f};
  f32x4 accA[2][2], accAL[2][2];
  #pragma unroll
  for (int m = 0; m < 2; ++m) { accA[m][0]=zz; accA[m][1]=zz; accAL[m][0]=zz; accAL[m][1]=zz; }

  const float* WfA1 = Wa1 + (size_t)aa*CIN*CH;
  const float* WfA2 = Wa2 + (size_t)aa*CIN*CH;
  const _Float16* wsA1 = wsw + OFF_WA1T + (size_t)aa*WA_PER;
  const _Float16* wsA2 = wsw + OFF_WA2T + (size_t)aa*WA_PER;

  // ---- layer A over 4 K-chunks (128,128,128,32) ----
  const int n  = t >> 3;
  const int sj = t & 7;
  #pragma unroll
  for (int ck = 0; ck < 4; ++ck) {
    const int koff = ck * 128;
    if (ck < 3) {
      const float* srow = sfea + ((size_t)n*L_SEQ + l)*CS + koff;
      const float* irow = sfei + ((size_t)n*L_SEQ + l)*CS + koff;
      #pragma unroll
      for (int u = 0; u < 4; ++u) {
        const int c = sj*16 + u*4;
        f16x4 h4, l4;
        splitrelu4(*reinterpret_cast<const float4*>(srow + c), h4, l4);
        *(f16x4*)(s1H + n*ABST + c) = h4;  *(f16x4*)(s1L + n*ABST + c) = l4;
        splitrelu4(*reinterpret_cast<const float4*>(irow + c), h4, l4);
        *(f16x4*)(s2H + n*ABST + c) = h4;  *(f16x4*)(s2L + n*ABST + c) = l4;
      }
    } else {
      const float* erow = encd + ((size_t)n*L_SEQ + l)*CE;
      const int c = sj*4;
      f16x4 h4, l4;
      splitrelu4(*reinterpret_cast<const float4*>(erow + c), h4, l4);
      *(f16x4*)(s1H + n*ABST + c) = h4;  *(f16x4*)(s1L + n*ABST + c) = l4;
      *(f16x4*)(s2H + n*ABST + c) = h4;  *(f16x4*)(s2L + n*ABST + c) = l4;
    }
    __syncthreads();
    const int nks = (ck < 3) ? 4 : 1;
    gemmA<USEWS>(s1H, s1L, WfA1, wsA1, koff, nks, accA, accAL, lane, h0);
    gemmA<USEWS>(s2H, s2L, WfA2, wsA2, koff, nks, accA, accAL, lane, h0);
    __syncthreads();
  }
  fold(accA, accAL,
       ba1[aa*CH + h0 + lr]      + ba2[aa*CH + h0 + lr],
       ba1[aa*CH + h0 + 16 + lr] + ba2[aa*CH + h0 + 16 + lr]);
  store_relu_pair(abH, abL, accA, lane, h0);   // writes s1 (dead post-barrier)
  __syncthreads();

  // ---- mid layers (ping-pong s1 <-> s2) ----
  { // h = relu(a)@Wb1a + bb1a
    f32x4 acc[2][2], accL[2][2];
    #pragma unroll
    for (int m = 0; m < 2; ++m) { acc[m][0]=zz; acc[m][1]=zz; accL[m][0]=zz; accL[m][1]=zz; }
    gemm128<USEWS>(abH, abL, Wb1a + (size_t)aa*WB_PER,
                   wsw + OFF_WB1AT + (size_t)aa*WB_PER, acc, accL, lane, h0);
    fold(acc, accL, bb1a[aa*CH + h0 + lr], bb1a[aa*CH + h0 + 16 + lr]);
    store_relu_pair(hbH, hbL, acc, lane, h0);
  }
  __syncthreads();
  { // a += relu(h)@Wb1b + bb1b
    f32x4 accL[2][2];
    #pragma unroll
    for (int m = 0; m < 2; ++m) { accL[m][0]=zz; accL[m][1]=zz; }
    gemm128<USEWS>(hbH, hbL, Wb1b + (size_t)aa*WB_PER,
                   wsw + OFF_WB1BT + (size_t)aa*WB_PER, accA, accL, lane, h0);
    fold(accA, accL, bb1b[aa*CH + h0 + lr], bb1b[aa*CH + h0 + 16 + lr]);
    store_relu_pair(abH, abL, accA, lane, h0);
  }
  __syncthreads();
  { // h = relu(a)@Wb2a + bb2a
    f32x4 acc[2][2], accL[2][2];
    #pragma unroll
    for (int m = 0; m < 2; ++m) { acc[m][0]=zz; acc[m][1]=zz; accL[m][0]=zz; accL[m][1]=zz; }
    gemm128<USEWS>(abH, abL, Wb2a + (size_t)aa*WB_PER,
                   wsw + OFF_WB2AT + (size_t)aa*WB_PER, acc, accL, lane, h0);
    fold(acc, accL, bb2a[aa*CH + h0 + lr], bb2a[aa*CH + h0 + 16 + lr]);
    store_relu_pair(hbH, hbL, acc, lane, h0);
  }
  __syncthreads();
  { // a += relu(h)@Wb2b + bb2b
    f32x4 accL[2][2];
    #pragma unroll
    for (int m = 0; m < 2; ++m) { accL[m][0]=zz; accL[m][1]=zz; }
    gemm128<USEWS>(hbH, hbL, Wb2b + (size_t)aa*WB_PER,
                   wsw + OFF_WB2BT + (size_t)aa*WB_PER, accA, accL, lane, h0);
    fold(accA, accL, bb2b[aa*CH + h0 + lr], bb2b[aa*CH + h0 + 16 + lr]);
    store_relu_pair(abH, abL, accA, lane, h0);
  }
  __syncthreads();

  // ---- out layer: relu(a) @ Wout (cols padded 14->16), pair-normalize ----
  if (wv < 2) {
    f32x4 o = zz, oL = zz;
    #pragma unroll
    for (int ks = 0; ks < 4; ++ks) {
      const int k = ks*32 + lk;
      const f16x8 ah = *(const f16x8*)(abH + (wv*16 + lr)*ABST + k);
      const f16x8 al = *(const f16x8*)(abL + (wv*16 + lr)*ABST + k);
      f16x8 bh, bl;
      if constexpr (USEWS) {
        const _Float16* p = wsw + OFF_WOUTT + (size_t)aa*WO_PER + (size_t)lr*CH + k;
        bh = *(const f16x8*)p; bl = *(const f16x8*)(p + TOTW);
      } else {
        if (lr < 14) {
          bfrag_f32(Wout + (size_t)aa*CH*14, 14, k, lr, bh, bl);
        } else {
          #pragma unroll
          for (int j = 0; j < 8; ++j) { bh[j] = (_Float16)0.f; bl[j] = (_Float16)0.f; }
        }
      }
      o  = MFMA16(ah, bh, o,  0,0,0);
      oL = MFMA16(ah, bl, oL, 0,0,0);
      oL = MFMA16(al, bh, oL, 0,0,0);
    }
    const float bo = (lr < 14) ? bout[aa*14 + lr] : 0.f;
    #pragma unroll
    for (int i = 0; i < 4; ++i) {
      const float v  = o[i] + oL[i]*ILOSCALE + bo;
      const float pv = __shfl_xor(v, 1);
      const float r  = rsqrtf(v*v + pv*pv + 1e-12f);
      if (lr < 14) {
        const int nrow = wv*16 + ((lane >> 4) << 2) + i;
        out[OUT_ANG + (size_t)nrow*(L_SEQ*14) + (size_t)l*14 + lr] = v*r;
      }
    }
  }
}

extern "C" void kernel_launch(void* const* d_in, const int* in_sizes, int n_in,
                              void* d_out, int out_size, void* d_ws, size_t ws_size,
                              hipStream_t stream) {
  const int*   aa   = (const int*)  d_in[0];
  const float* sfea = (const float*)d_in[1];
  const float* sfei = (const float*)d_in[2];
  const float* encd = (const float*)d_in[3];
  const float* quat = (const float*)d_in[4];
  const float* trsl = (const float*)d_in[5];
  const float* Wq   = (const float*)d_in[6];
  const float* bq   = (const float*)d_in[7];
  const float* Wt   = (const float*)d_in[8];
  const float* bt   = (const float*)d_in[9];
  const float* Wa1  = (const float*)d_in[10];
  const float* ba1  = (const float*)d_in[11];
  const float* Wa2  = (const float*)d_in[12];
  const float* ba2  = (const float*)d_in[13];
  const float* Wb1a = (const float*)d_in[14];
  const float* bb1a = (const float*)d_in[15];
  const float* Wb1b = (const float*)d_in[16];
  const float* bb1b = (const float*)d_in[17];
  const float* Wb2a = (const float*)d_in[18];
  const float* bb2a = (const float*)d_in[19];
  const float* Wb2b = (const float*)d_in[20];
  const float* bb2b = (const float*)d_in[21];
  const float* Wout = (const float*)d_in[22];
  const float* bout = (const float*)d_in[23];
  float* out = (float*)d_out;

  const bool useperm = ws_size >= (size_t)PERM_BYTES;
  const bool usews   = ws_size >= WS_NEED;
  int* perm = useperm ? (int*)d_ws : nullptr;
  _Float16* wsw = (_Float16*)((char*)d_ws + PERM_BYTES);

  if (useperm)
    hipLaunchKernelGGL(build_perm, dim3(1), dim3(1024), 0, stream, aa, perm);
  if (usews)
    hipLaunchKernelGGL(convert_w, dim3((TOTW + 255)/256), dim3(256), 0, stream,
                       Wa1, Wa2, Wb1a, Wb1b, Wb2a, Wb2b, Wout, wsw);
  hipLaunchKernelGGL(quat_head, dim3(16384), dim3(256), 0, stream,
                     sfea, encd, quat, trsl, Wq, bq, Wt, bt, out);
  if (usews)
    hipLaunchKernelGGL((fah_main<true>), dim3(L_SEQ), dim3(256), 0, stream,
                       aa, perm, sfea, sfei, encd,
                       Wa1, Wa2, Wb1a, Wb1b, Wb2a, Wb2b, Wout,
                       ba1, ba2, bb1a, bb1b, bb2a, bb2b, bout, wsw, out);
  else
    hipLaunchKernelGGL((fah_main<false>), dim3(L_SEQ), dim3(256), 0, stream,
                       aa, perm, sfea, sfei, encd,
                       Wa1, Wa2, Wb1a, Wb1b, Wb2a, Wb2b, Wout,
                       ba1, ba2, bb1a, bb1b, bb2a, bb2b, bout, wsw, out);
}

// Round 10
// 209.213 us; speedup vs baseline: 1.6812x; 1.0482x over previous
//
#include <hip/hip_runtime.h>

#define L_SEQ 2048
#define CS 384
#define CE 32
#define CIN 416
#define CH 128
#define NRES 20

#define ABST 136   // f16 LDS row stride (272 B)
#define PADN 2068  // 2048 + 20 (max padding), even
#define NB2  1034  // PADN/2 blocks

// ---- ws layout: [u16 perm, 4608 B region][f16 hi weights TOTW][f16 lo weights TOTW]
#define PERM_REGION 4608
#define WA_PER (CH*CIN)
#define WB_PER (CH*CH)
#define WO_PER (16*CH)
#define OFF_WA1T 0
#define OFF_WA2T (NRES*WA_PER)
#define OFF_WB1AT (2*NRES*WA_PER)
#define OFF_WB1BT (OFF_WB1AT + 1*NRES*WB_PER)
#define OFF_WB2AT (OFF_WB1AT + 2*NRES*WB_PER)
#define OFF_WB2BT (OFF_WB1AT + 3*NRES*WB_PER)
#define OFF_WOUTT (OFF_WB1AT + 4*NRES*WB_PER)
#define TOTW (OFF_WOUTT + NRES*WO_PER)   // 3,481,600 elements

// output offsets (floats): quat_new, trsl_new, angl, quat_upd
#define OUT_TR 262144
#define OUT_ANG 458752
#define OUT_QU 1376256

#define LOSCALE 4096.0f
#define ILOSCALE (1.0f/4096.0f)
#define F16MIN 6.1035156e-5f

typedef _Float16 f16x8 __attribute__((ext_vector_type(8)));
typedef _Float16 f16x4 __attribute__((ext_vector_type(4)));
typedef float f32x4 __attribute__((ext_vector_type(4)));

#define MFMA16 __builtin_amdgcn_mfma_f32_16x16x32_f16

// ---------------- split helpers (x = hi + lo/4096, denormal-safe) ----------------
static __device__ __forceinline__ void split1(float x, _Float16& h, _Float16& l) {
  _Float16 hi = (__builtin_fabsf(x) < F16MIN) ? (_Float16)0.f : (_Float16)x;
  h = hi;
  l = (_Float16)((x - (float)hi) * LOSCALE);
}

// ---------------- quat/trsl head: one wave per (n,l) — PROVEN (rounds 4/5) ----------------
__global__ __launch_bounds__(256) void quat_head(
    const float* __restrict__ sfea, const float* __restrict__ encd,
    const float* __restrict__ quat, const float* __restrict__ trsl,
    const float* __restrict__ Wq, const float* __restrict__ bq,
    const float* __restrict__ Wt, const float* __restrict__ bt,
    float* __restrict__ out) {
  const int wv   = threadIdx.x >> 6;
  const int lane = threadIdx.x & 63;
  const size_t idx = (size_t)blockIdx.x * 4 + wv;
  const float* __restrict__ srow = sfea + idx * CS;

  float q0=0,q1=0,q2=0,q3=0,t0=0,t1=0,t2=0;
  #pragma unroll
  for (int cc = 0; cc < 6; ++cc) {
    const int ch = cc*64 + lane;
    const float s = srow[ch];
    const float4 wq = *reinterpret_cast<const float4*>(Wq + (size_t)ch*4);
    const float* wt = Wt + (size_t)ch*3;
    q0 += s*wq.x; q1 += s*wq.y; q2 += s*wq.z; q3 += s*wq.w;
    t0 += s*wt[0]; t1 += s*wt[1]; t2 += s*wt[2];
  }
  if (lane < CE) {
    const float s = encd[idx*CE + lane];
    const int ch = CS + lane;
    const float4 wq = *reinterpret_cast<const float4*>(Wq + (size_t)ch*4);
    const float* wt = Wt + (size_t)ch*3;
    q0 += s*wq.x; q1 += s*wq.y; q2 += s*wq.z; q3 += s*wq.w;
    t0 += s*wt[0]; t1 += s*wt[1]; t2 += s*wt[2];
  }
  #pragma unroll
  for (int off = 1; off < 64; off <<= 1) {
    q0 += __shfl_xor(q0, off); q1 += __shfl_xor(q1, off);
    q2 += __shfl_xor(q2, off); q3 += __shfl_xor(q3, off);
    t0 += __shfl_xor(t0, off); t1 += __shfl_xor(t1, off);
    t2 += __shfl_xor(t2, off);
  }
  if (lane == 0) {
    const float u0 = q0 + bq[0], u1 = q1 + bq[1], u2 = q2 + bq[2], u3 = q3 + bq[3];
    const float v0 = t0 + bt[0], v1 = t1 + bt[1], v2 = t2 + bt[2];
    float a0 = quat[idx*4+0], a1 = quat[idx*4+1], a2 = quat[idx*4+2], a3 = quat[idx*4+3];
    const float rq = rsqrtf(a0*a0+a1*a1+a2*a2+a3*a3 + 1e-8f);
    a0*=rq; a1*=rq; a2*=rq; a3*=rq;
    const float ru = rsqrtf(u0*u0+u1*u1+u2*u2+u3*u3 + 1e-8f);
    const float p0=u0*ru, p1=u1*ru, p2=u2*ru, p3=u3*ru;
    const float mw = a0*p0 - a1*p1 - a2*p2 - a3*p3;
    const float mx = a0*p1 + a1*p0 + a2*p3 - a3*p2;
    const float my = a0*p2 - a1*p3 + a2*p0 + a3*p1;
    const float mz = a0*p3 + a1*p2 - a2*p1 + a3*p0;
    const float rm = rsqrtf(mw*mw+mx*mx+my*my+mz*mz + 1e-8f);
    out[idx*4+0]=mw*rm; out[idx*4+1]=mx*rm; out[idx*4+2]=my*rm; out[idx*4+3]=mz*rm;
    const float tx = 2.f*(a2*v2 - a3*v1);
    const float ty = 2.f*(a3*v0 - a1*v2);
    const float tz = 2.f*(a1*v1 - a2*v0);
    out[OUT_TR + idx*3+0] = trsl[idx*3+0] + v0 + a0*tx + (a2*tz - a3*ty);
    out[OUT_TR + idx*3+1] = trsl[idx*3+1] + v1 + a0*ty + (a3*tx - a1*tz);
    out[OUT_TR + idx*3+2] = trsl[idx*3+2] + v2 + a0*tz + (a1*ty - a2*tx);
    out[OUT_QU + idx*4+0]=u0; out[OUT_QU + idx*4+1]=u1;
    out[OUT_QU + idx*4+2]=u2; out[OUT_QU + idx*4+3]=u3;
  }
}

// ------- aa-grouped, pair-padded l-permutation (u16), wave-parallel -------
__global__ __launch_bounds__(1024) void build_perm(const int* __restrict__ aa_seq,
                                                   unsigned short* __restrict__ perm) {
  __shared__ int cnt[NRES*32];
  __shared__ int woff[NRES*32];
  __shared__ int poff_s[NRES];
  __shared__ int ctot_s[NRES];
  const int t = threadIdx.x;
  const int wv = t >> 6, lane = t & 63;

  for (int i = t; i < PADN; i += 1024) perm[i] = 0;   // tail filler -> l=0 dups

  int aav[2];
  #pragma unroll
  for (int h = 0; h < 2; ++h) {
    const int W = wv + h*16;
    aav[h] = aa_seq[W*64 + lane];
    #pragma unroll
    for (int a = 0; a < NRES; ++a) {
      const unsigned long long m = __ballot(aav[h] == a);
      if (lane == a) cnt[a*32 + W] = (int)__popcll(m);
    }
  }
  __syncthreads();
  if (t < 32) {
    int tot = 0;
    if (t < NRES) {
      #pragma unroll
      for (int W = 0; W < 32; ++W) tot += cnt[t*32 + W];
    }
    const int pa = (t < NRES) ? ((tot + 1) & ~1) : 0;   // pad group to even
    int s = pa;
    #pragma unroll
    for (int o = 1; o < 32; o <<= 1) {
      const int u = __shfl_up(s, o);
      if (lane >= o) s += u;
    }
    if (t < NRES) { poff_s[t] = s - pa; ctot_s[t] = tot; }
    for (int a = 0; a < NRES; ++a) {
      const int v0 = cnt[a*32 + t];
      int v = v0;
      #pragma unroll
      for (int o = 1; o < 32; o <<= 1) {
        const int u = __shfl_up(v, o);
        if (lane >= o) v += u;
      }
      woff[a*32 + t] = poff_s[a] + v - v0;
    }
  }
  __syncthreads();
  const unsigned long long ltmask = (lane == 0) ? 0ull : (~0ull >> (64 - lane));
  #pragma unroll
  for (int h = 0; h < 2; ++h) {
    const int W = wv + h*16;
    const int a = aav[h];
    int pos = 0;
    #pragma unroll
    for (int aq = 0; aq < NRES; ++aq) {
      const unsigned long long m = __ballot(a == aq);
      if (a == aq) pos = woff[aq*32 + W] + (int)__popcll(m & ltmask);
    }
    const unsigned short lv = (unsigned short)(W*64 + lane);
    perm[pos] = lv;
    if ((ctot_s[a] & 1) && pos == poff_s[a] + ctot_s[a] - 1) perm[pos + 1] = lv;  // pad dup
  }
}

// ---------------- weight convert: f32 -> transposed f16 hi/lo pairs ----------------
__global__ __launch_bounds__(256) void convert_w(
    const float* __restrict__ Wa1, const float* __restrict__ Wa2,
    const float* __restrict__ Wb1a, const float* __restrict__ Wb1b,
    const float* __restrict__ Wb2a, const float* __restrict__ Wb2b,
    const float* __restrict__ Wout, _Float16* __restrict__ wsw) {
  const int idx = blockIdx.x * 256 + threadIdx.x;
  if (idx >= TOTW) return;
  float v;
  if (idx < OFF_WB1AT) {
    const int which = (idx < OFF_WA2T) ? 0 : 1;
    const float* W = which ? Wa2 : Wa1;
    int r = idx - which * OFF_WA2T;
    const int aa = r / WA_PER; r -= aa * WA_PER;
    const int h = r / CIN;     const int c = r - h * CIN;
    v = W[((size_t)aa*CIN + c)*CH + h];                 // -> ws[aa][h][c]
  } else if (idx < OFF_WOUTT) {
    int q = idx - OFF_WB1AT;
    const int which = q / (NRES*WB_PER);
    int r = q - which * (NRES*WB_PER);
    const float* W = (which==0)?Wb1a:(which==1)?Wb1b:(which==2)?Wb2a:Wb2b;
    const int aa = r / WB_PER; r -= aa * WB_PER;
    const int h = r / CH;      const int c = r - h * CH;
    v = W[((size_t)aa*CH + c)*CH + h];
  } else {
    int r = idx - OFF_WOUTT;
    const int aa = r / WO_PER; r -= aa * WO_PER;
    const int kk = r / CH;     const int c = r - kk * CH;
    v = (kk < 14) ? Wout[((size_t)aa*CH + c)*14 + kk] : 0.f;
  }
  _Float16 h, l; split1(v, h, l);
  wsw[idx] = h;
  wsw[(size_t)TOTW + idx] = l;
}

// ---------------- fragment / epilogue helpers ----------------
static __device__ __forceinline__ void fold(f32x4 acc[2][2], const f32x4 accL[2][2],
                                            float b0, float b1) {
  #pragma unroll
  for (int m = 0; m < 2; ++m)
    #pragma unroll
    for (int i = 0; i < 4; ++i) {
      acc[m][0][i] += accL[m][0][i]*ILOSCALE + b0;
      acc[m][1][i] += accL[m][1][i]*ILOSCALE + b1;
    }
}

static __device__ __forceinline__ void store_relu_pair(_Float16* dh, _Float16* dl,
    const f32x4 acc[2][2], int lane, int h0) {
  const int lr = lane & 15;
  const int r0 = (lane >> 4) << 2;
  #pragma unroll
  for (int m = 0; m < 2; ++m)
    #pragma unroll
    for (int p = 0; p < 2; ++p)
      #pragma unroll
      for (int i = 0; i < 4; ++i) {
        const float v = fmaxf(acc[m][p][i], 0.f);
        _Float16 hh, ll; split1(v, hh, ll);
        const int idx = (m*16 + r0 + i)*ABST + h0 + p*16 + lr;
        dh[idx] = hh; dl[idx] = ll;
      }
}

// dual-position GEMM step: one B-fragment load feeds both positions (same aa)
template<int S>
static __device__ __forceinline__ void gemm_dual(
    const _Float16* aH0, const _Float16* aL0,
    const _Float16* aH1, const _Float16* aL1,
    const _Float16* __restrict__ wH,
    int kbase, int nks,
    f32x4 acc0[2][2], f32x4 acc0L[2][2],
    f32x4 acc1[2][2], f32x4 acc1L[2][2],
    int lane, int h0) {
  const int lr = lane & 15;
  const int lk = (lane >> 4) << 3;
  #pragma unroll
  for (int ks = 0; ks < nks; ++ks) {
    const int kl = ks*32 + lk;
    const int kg = kbase + kl;
    const _Float16* p0 = wH + (size_t)(h0+lr)*S + kg;
    const _Float16* p1 = wH + (size_t)(h0+16+lr)*S + kg;
    const f16x8 b0h = *(const f16x8*)p0;
    const f16x8 b0l = *(const f16x8*)(p0 + TOTW);
    const f16x8 b1h = *(const f16x8*)p1;
    const f16x8 b1l = *(const f16x8*)(p1 + TOTW);
#define DOPOS(AH, AL, AC, ACL) { \
    const f16x8 a0h = *(const f16x8*)(AH + lr*ABST + kl); \
    const f16x8 a0l = *(const f16x8*)(AL + lr*ABST + kl); \
    const f16x8 a1h = *(const f16x8*)(AH + (lr+16)*ABST + kl); \
    const f16x8 a1l = *(const f16x8*)(AL + (lr+16)*ABST + kl); \
    AC[0][0]  = MFMA16(a0h, b0h, AC[0][0], 0,0,0); \
    ACL[0][0] = MFMA16(a0h, b0l, ACL[0][0], 0,0,0); \
    ACL[0][0] = MFMA16(a0l, b0h, ACL[0][0], 0,0,0); \
    AC[1][0]  = MFMA16(a1h, b0h, AC[1][0], 0,0,0); \
    ACL[1][0] = MFMA16(a1h, b0l, ACL[1][0], 0,0,0); \
    ACL[1][0] = MFMA16(a1l, b0h, ACL[1][0], 0,0,0); \
    AC[0][1]  = MFMA16(a0h, b1h, AC[0][1], 0,0,0); \
    ACL[0][1] = MFMA16(a0h, b1l, ACL[0][1], 0,0,0); \
    ACL[0][1] = MFMA16(a0l, b1h, ACL[0][1], 0,0,0); \
    AC[1][1]  = MFMA16(a1h, b1h, AC[1][1], 0,0,0); \
    ACL[1][1] = MFMA16(a1h, b1l, ACL[1][1], 0,0,0); \
    ACL[1][1] = MFMA16(a1l, b1h, ACL[1][1], 0,0,0); }
    DOPOS(aH0, aL0, acc0, acc0L)
    DOPOS(aH1, aL1, acc1, acc1L)
#undef DOPOS
  }
}

// stage one 128-col chunk of a row (relu'd f16 hi/lo) — NO quat fusion this round
static __device__ __forceinline__ void stage_row128(
    const float* __restrict__ row, _Float16* dH, _Float16* dL, int n, int sj) {
  #pragma unroll
  for (int q2 = 0; q2 < 2; ++q2) {
    const int cl = q2*64 + sj*8;
    const float4 v0 = *(const float4*)(row + cl);
    const float4 v1 = *(const float4*)(row + cl + 4);
    const float xs[8] = {v0.x,v0.y,v0.z,v0.w,v1.x,v1.y,v1.z,v1.w};
    f16x8 h8, l8;
    #pragma unroll
    for (int e = 0; e < 8; ++e) {
      _Float16 hh, ll; split1(fmaxf(xs[e], 0.f), hh, ll);
      h8[e] = hh; l8[e] = ll;
    }
    *(f16x8*)(dH + n*ABST + cl) = h8;
    *(f16x8*)(dL + n*ABST + cl) = l8;
  }
}

static __device__ __forceinline__ void stage_encd(
    const float* __restrict__ erow,
    _Float16* sH, _Float16* sL, _Float16* iH, _Float16* iL, int n, int sj) {
  const int cl = sj*4;
  const float4 v = *(const float4*)(erow + cl);
  const float xs[4] = {v.x, v.y, v.z, v.w};
  f16x4 h4, l4;
  #pragma unroll
  for (int e = 0; e < 4; ++e) {
    _Float16 hh, ll; split1(fmaxf(xs[e], 0.f), hh, ll);
    h4[e] = hh; l4[e] = ll;
  }
  *(f16x4*)(sH + n*ABST + cl) = h4;  *(f16x4*)(sL + n*ABST + cl) = l4;
  *(f16x4*)(iH + n*ABST + cl) = h4;  *(f16x4*)(iL + n*ABST + cl) = l4;
}

// ---------------- angle net: one block per PAIR of same-aa positions ----------------
__global__ __launch_bounds__(256, 2) void fah_main(
    const int* __restrict__ aa_seq, const unsigned short* __restrict__ perm,
    const float* __restrict__ sfea, const float* __restrict__ sfei,
    const float* __restrict__ encd,
    const float* __restrict__ ba1, const float* __restrict__ ba2,
    const float* __restrict__ bb1a, const float* __restrict__ bb1b,
    const float* __restrict__ bb2a, const float* __restrict__ bb2b,
    const float* __restrict__ bout,
    const _Float16* __restrict__ wsw,
    float* __restrict__ out) {
  __shared__ __align__(16) _Float16 sf0H[32*ABST], sf0L[32*ABST];
  __shared__ __align__(16) _Float16 in0H[32*ABST], in0L[32*ABST];
  __shared__ __align__(16) _Float16 sf1H[32*ABST], sf1L[32*ABST];
  __shared__ __align__(16) _Float16 in1H[32*ABST], in1L[32*ABST];
  _Float16 *ab0H = sf0H, *ab0L = sf0L, *hb0H = in0H, *hb0L = in0L;
  _Float16 *ab1H = sf1H, *ab1L = sf1L, *hb1H = in1H, *hb1L = in1L;

  // bijective XCD-chunked swizzle: NB2=1034 = 2*130 + 6*129
  const int orig = blockIdx.x;
  const int xcd = orig & 7, i8 = orig >> 3;
  const int sp = (xcd < 2 ? xcd*130 : 260 + (xcd-2)*129) + i8;
  const int l0 = perm[2*sp], l1 = perm[2*sp+1];
  const int aa = aa_seq[l0];          // == aa_seq[l1] by construction

  const int t = threadIdx.x;
  const int lane = t & 63, wv = t >> 6;
  const int lr = lane & 15, lk = (lane >> 4) << 3, h0 = wv * 32;
  const int n = t >> 3, sj = t & 7;

  const f32x4 zz = {0.f, 0.f, 0.f, 0.f};
  f32x4 accA0[2][2], accA0L[2][2], accA1[2][2], accA1L[2][2];
  #pragma unroll
  for (int m = 0; m < 2; ++m) {
    accA0[m][0]=zz; accA0[m][1]=zz; accA0L[m][0]=zz; accA0L[m][1]=zz;
    accA1[m][0]=zz; accA1[m][1]=zz; accA1L[m][0]=zz; accA1L[m][1]=zz;
  }

  const _Float16* wsA1 = wsw + OFF_WA1T + (size_t)aa*WA_PER;
  const _Float16* wsA2 = wsw + OFF_WA2T + (size_t)aa*WA_PER;

  // ---- layer A over 4 K-chunks (128,128,128,32) ----
  #pragma unroll
  for (int ck = 0; ck < 4; ++ck) {
    const int koff = ck * 128;
    if (ck < 3) {
      stage_row128(sfea + ((size_t)n*L_SEQ + l0)*CS + koff, sf0H, sf0L, n, sj);
      stage_row128(sfei + ((size_t)n*L_SEQ + l0)*CS + koff, in0H, in0L, n, sj);
      stage_row128(sfea + ((size_t)n*L_SEQ + l1)*CS + koff, sf1H, sf1L, n, sj);
      stage_row128(sfei + ((size_t)n*L_SEQ + l1)*CS + koff, in1H, in1L, n, sj);
    } else {
      stage_encd(encd + ((size_t)n*L_SEQ + l0)*CE, sf0H, sf0L, in0H, in0L, n, sj);
      stage_encd(encd + ((size_t)n*L_SEQ + l1)*CE, sf1H, sf1L, in1H, in1L, n, sj);
    }
    __syncthreads();
    const int nks = (ck < 3) ? 4 : 1;
    gemm_dual<CIN>(sf0H, sf0L, sf1H, sf1L, wsA1, koff, nks,
                   accA0, accA0L, accA1, accA1L, lane, h0);
    gemm_dual<CIN>(in0H, in0L, in1H, in1L, wsA2, koff, nks,
                   accA0, accA0L, accA1, accA1L, lane, h0);
    __syncthreads();
  }

  { // layer-A fold + store (sf arrays are dead -> become ab)
    const float b0v = ba1[aa*CH + h0 + lr]      + ba2[aa*CH + h0 + lr];
    const float b1v = ba1[aa*CH + h0 + 16 + lr] + ba2[aa*CH + h0 + 16 + lr];
    fold(accA0, accA0L, b0v, b1v);
    fold(accA1, accA1L, b0v, b1v);
    store_relu_pair(ab0H, ab0L, accA0, lane, h0);
    store_relu_pair(ab1H, ab1L, accA1, lane, h0);
  }
  __syncthreads();

  { // h = relu(a)@Wb1a + bb1a
    f32x4 c0[2][2], c0L[2][2], c1[2][2], c1L[2][2];
    #pragma unroll
    for (int m = 0; m < 2; ++m) { c0[m][0]=zz;c0[m][1]=zz;c0L[m][0]=zz;c0L[m][1]=zz;
                                  c1[m][0]=zz;c1[m][1]=zz;c1L[m][0]=zz;c1L[m][1]=zz; }
    gemm_dual<CH>(ab0H, ab0L, ab1H, ab1L, wsw + OFF_WB1AT + (size_t)aa*WB_PER, 0, 4,
                  c0, c0L, c1, c1L, lane, h0);
    const float B0 = bb1a[aa*CH + h0 + lr], B1 = bb1a[aa*CH + h0 + 16 + lr];
    fold(c0, c0L, B0, B1); fold(c1, c1L, B0, B1);
    store_relu_pair(hb0H, hb0L, c0, lane, h0);
    store_relu_pair(hb1H, hb1L, c1, lane, h0);
  }
  __syncthreads();
  { // a += relu(h)@Wb1b + bb1b
    f32x4 c0L[2][2], c1L[2][2];
    #pragma unroll
    for (int m = 0; m < 2; ++m) { c0L[m][0]=zz;c0L[m][1]=zz;c1L[m][0]=zz;c1L[m][1]=zz; }
    gemm_dual<CH>(hb0H, hb0L, hb1H, hb1L, wsw + OFF_WB1BT + (size_t)aa*WB_PER, 0, 4,
                  accA0, c0L, accA1, c1L, lane, h0);
    const float B0 = bb1b[aa*CH + h0 + lr], B1 = bb1b[aa*CH + h0 + 16 + lr];
    fold(accA0, c0L, B0, B1); fold(accA1, c1L, B0, B1);
    store_relu_pair(ab0H, ab0L, accA0, lane, h0);
    store_relu_pair(ab1H, ab1L, accA1, lane, h0);
  }
  __syncthreads();
  { // h = relu(a)@Wb2a + bb2a
    f32x4 c0[2][2], c0L[2][2], c1[2][2], c1L[2][2];
    #pragma unroll
    for (int m = 0; m < 2; ++m) { c0[m][0]=zz;c0[m][1]=zz;c0L[m][0]=zz;c0L[m][1]=zz;
                                  c1[m][0]=zz;c1[m][1]=zz;c1L[m][0]=zz;c1L[m][1]=zz; }
    gemm_dual<CH>(ab0H, ab0L, ab1H, ab1L, wsw + OFF_WB2AT + (size_t)aa*WB_PER, 0, 4,
                  c0, c0L, c1, c1L, lane, h0);
    const float B0 = bb2a[aa*CH + h0 + lr], B1 = bb2a[aa*CH + h0 + 16 + lr];
    fold(c0, c0L, B0, B1); fold(c1, c1L, B0, B1);
    store_relu_pair(hb0H, hb0L, c0, lane, h0);
    store_relu_pair(hb1H, hb1L, c1, lane, h0);
  }
  __syncthreads();
  { // a += relu(h)@Wb2b + bb2b
    f32x4 c0L[2][2], c1L[2][2];
    #pragma unroll
    for (int m = 0; m < 2; ++m) { c0L[m][0]=zz;c0L[m][1]=zz;c1L[m][0]=zz;c1L[m][1]=zz; }
    gemm_dual<CH>(hb0H, hb0L, hb1H, hb1L, wsw + OFF_WB2BT + (size_t)aa*WB_PER, 0, 4,
                  accA0, c0L, accA1, c1L, lane, h0);
    const float B0 = bb2b[aa*CH + h0 + lr], B1 = bb2b[aa*CH + h0 + 16 + lr];
    fold(accA0, c0L, B0, B1); fold(accA1, c1L, B0, B1);
    store_relu_pair(ab0H, ab0L, accA0, lane, h0);
    store_relu_pair(ab1H, ab1L, accA1, lane, h0);
  }
  __syncthreads();

  // ---- out layer: waves 0,1 -> pos0; waves 2,3 -> pos1 ----
  {
    const int pos  = wv >> 1;
    const int half = wv & 1;
    const _Float16* aH = pos ? ab1H : ab0H;
    const _Float16* aL = pos ? ab1L : ab0L;
    const int lsel = pos ? l1 : l0;
    f32x4 o = zz, oL = zz;
    #pragma unroll
    for (int ks = 0; ks < 4; ++ks) {
      const int k = ks*32 + lk;
      const f16x8 ah = *(const f16x8*)(aH + (half*16 + lr)*ABST + k);
      const f16x8 al = *(const f16x8*)(aL + (half*16 + lr)*ABST + k);
      const _Float16* p = wsw + OFF_WOUTT + (size_t)aa*WO_PER + (size_t)lr*CH + k;
      const f16x8 bh = *(const f16x8*)p;
      const f16x8 bl = *(const f16x8*)(p + TOTW);
      o  = MFMA16(ah, bh, o,  0,0,0);
      oL = MFMA16(ah, bl, oL, 0,0,0);
      oL = MFMA16(al, bh, oL, 0,0,0);
    }
    const float bo = (lr < 14) ? bout[aa*14 + lr] : 0.f;
    #pragma unroll
    for (int i = 0; i < 4; ++i) {
      const float v  = o[i] + oL[i]*ILOSCALE + bo;
      const float pv = __shfl_xor(v, 1);
      const float r  = rsqrtf(v*v + pv*pv + 1e-12f);
      if (lr < 14) {
        const int nrow = half*16 + ((lane >> 4) << 2) + i;
        out[OUT_ANG + (size_t)nrow*(L_SEQ*14) + (size_t)lsel*14 + lr] = v*r;
      }
    }
  }
}

extern "C" void kernel_launch(void* const* d_in, const int* in_sizes, int n_in,
                              void* d_out, int out_size, void* d_ws, size_t ws_size,
                              hipStream_t stream) {
  const int*   aa   = (const int*)  d_in[0];
  const float* sfea = (const float*)d_in[1];
  const float* sfei = (const float*)d_in[2];
  const float* encd = (const float*)d_in[3];
  const float* quat = (const float*)d_in[4];
  const float* trsl = (const float*)d_in[5];
  const float* Wq   = (const float*)d_in[6];
  const float* bq   = (const float*)d_in[7];
  const float* Wt   = (const float*)d_in[8];
  const float* bt   = (const float*)d_in[9];
  const float* Wa1  = (const float*)d_in[10];
  const float* ba1  = (const float*)d_in[11];
  const float* Wa2  = (const float*)d_in[12];
  const float* ba2  = (const float*)d_in[13];
  const float* Wb1a = (const float*)d_in[14];
  const float* bb1a = (const float*)d_in[15];
  const float* Wb1b = (const float*)d_in[16];
  const float* bb1b = (const float*)d_in[17];
  const float* Wb2a = (const float*)d_in[18];
  const float* bb2a = (const float*)d_in[19];
  const float* Wb2b = (const float*)d_in[20];
  const float* bb2b = (const float*)d_in[21];
  const float* Wout = (const float*)d_in[22];
  const float* bout = (const float*)d_in[23];
  float* out = (float*)d_out;

  unsigned short* perm = (unsigned short*)d_ws;
  _Float16* wsw = (_Float16*)((char*)d_ws + PERM_REGION);

  hipLaunchKernelGGL(build_perm, dim3(1), dim3(1024), 0, stream, aa, perm);
  hipLaunchKernelGGL(convert_w, dim3((TOTW + 255)/256), dim3(256), 0, stream,
                     Wa1, Wa2, Wb1a, Wb1b, Wb2a, Wb2b, Wout, wsw);
  hipLaunchKernelGGL(quat_head, dim3(16384), dim3(256), 0, stream,
                     sfea, encd, quat, trsl, Wq, bq, Wt, bt, out);
  hipLaunchKernelGGL(fah_main, dim3(NB2), dim3(256), 0, stream,
                     aa, perm, sfea, sfei, encd,
                     ba1, ba2, bb1a, bb1b, bb2a, bb2b, bout, wsw, out);
}